// Round 11
// baseline (165.953 us; speedup 1.0000x reference)
//
#include <hip/hip_runtime.h>
#include <hip/hip_bf16.h>
#include <stdint.h>

// GPT2Attention: S=2048 E=1024 H=16 d=64 T=4096 past=2048, f32 in/out.
// Round 11: attn VALU/latency diet on the r10 structure (r8-r10 showed occupancy
// and DS-count are NOT the levers; VALU instr count + cross-lane latency are):
//  - native (__bf16) casts -> v_cvt_pk_bf16_f32 (replaces ~130 manual-pack ops)
//  - v_permlane32_swap_b32 pa-build (VALU crossbar; replaces 8 ds_bpermute +
//    16 cndmask; both outputs usable)
//  - wave-uniform if(partial) -> mask VALU only in masked tiles
//  - hoisted zero f32x16 as first-MFMA C operand (no per-tile s-init movs)
// Grid/chunking/head-affinity/merge identical to r9/r10.

#define S_LEN 2048
#define E_DIM 1024
#define NHEAD 16
#define HDIM  64
#define T_LEN 4096
#define PASTL 2048

typedef __bf16 bf16x8 __attribute__((ext_vector_type(8)));
typedef __bf16 bf16x2 __attribute__((ext_vector_type(2)));
typedef float  f32x4  __attribute__((ext_vector_type(4)));
typedef float  f32x16 __attribute__((ext_vector_type(16)));

static __device__ __forceinline__ f32x4 mfma_bf16(bf16x8 a, bf16x8 b, f32x4 c) {
  return __builtin_amdgcn_mfma_f32_16x16x32_bf16(a, b, c, 0, 0, 0);
}
static __device__ __forceinline__ f32x16 mfma32(bf16x8 a, bf16x8 b, f32x16 c) {
  return __builtin_amdgcn_mfma_f32_32x32x16_bf16(a, b, c, 0, 0, 0);
}

// RNE float -> bf16 bits
static __device__ __forceinline__ unsigned int f2bf(float f) {
  union { float f; unsigned int u; } v; v.f = f;
  unsigned int u = v.u;
  return (u + 0x7fffu + ((u >> 16) & 1u)) >> 16;
}

static __device__ __forceinline__ float bf2f(unsigned short u) {
  union { unsigned int u; float f; } v; v.u = (unsigned int)u << 16;
  return v.f;
}

// packed 2xf32 -> 1 dword of 2xbf16 (compiler emits v_cvt_pk_bf16_f32)
static __device__ __forceinline__ unsigned pkbf(float lo, float hi) {
  bf16x2 t = {(__bf16)lo, (__bf16)hi};
  return __builtin_bit_cast(unsigned, t);
}

// v_permlane32_swap_b32: a' = a.lo32lanes || b.lo32lanes ; b' = a.hi || b.hi
static __device__ __forceinline__ void plswap(unsigned &a, unsigned &b) {
  asm volatile("v_permlane32_swap_b32 %0, %1" : "+v"(a), "+v"(b));
}

#define GLOBAL_LOAD_LDS16(gptr, lptr)                                              \
  __builtin_amdgcn_global_load_lds(                                                \
      (const __attribute__((address_space(1))) unsigned int*)(gptr),               \
      (__attribute__((address_space(3))) unsigned int*)(lptr), 16, 0, 0)

// ---------------------------------------------------------------- aux kernels

__global__ void copy_past_kernel(const float* __restrict__ past,
                                 float* __restrict__ cache,
                                 unsigned short* __restrict__ kb) {
  const int n4 = (2 * NHEAD * PASTL * HDIM) / 4;
  for (int i = blockIdx.x * blockDim.x + threadIdx.x; i < n4;
       i += gridDim.x * blockDim.x) {
    int e = i * 4;
    int d = e & 63;
    int t = (e >> 6) & (PASTL - 1);
    int hh = (e >> 17) & (NHEAD - 1);
    int kv = e >> 21;
    size_t full = (((size_t)kv * NHEAD + hh) * T_LEN + t) * HDIM + d;
    float4 v = *(const float4*)(past + full);
    *(float4*)(cache + full) = v;
    if (kv == 0) {
      ushort4 u;
      u.x = f2bf(v.x); u.y = f2bf(v.y); u.z = f2bf(v.z); u.w = f2bf(v.w);
      *(ushort4*)(kb + full) = u;
    }
  }
}

__global__ void convert_kernel(const float* __restrict__ in,
                               unsigned short* __restrict__ out, int n4) {
  for (int i = blockIdx.x * blockDim.x + threadIdx.x; i < n4;
       i += gridDim.x * blockDim.x) {
    float4 v = ((const float4*)in)[i];
    ushort4 u;
    u.x = f2bf(v.x); u.y = f2bf(v.y); u.z = f2bf(v.z); u.w = f2bf(v.w);
    ((ushort4*)out)[i] = u;
  }
}

// in [rows][cols] f32 -> out [cols][rows] bf16
__global__ void transpose_convert_kernel(const float* __restrict__ in,
                                         unsigned short* __restrict__ out,
                                         int rows, int cols) {
  __shared__ float tile[64][65];
  const int c0 = blockIdx.x * 64, r0 = blockIdx.y * 64;
  const int tx = threadIdx.x & 63, ty = threadIdx.x >> 6;
#pragma unroll
  for (int r = 0; r < 64; r += 4)
    tile[r + ty][tx] = in[(size_t)(r0 + r + ty) * cols + c0 + tx];
  __syncthreads();
#pragma unroll
  for (int r = 0; r < 64; r += 4)
    out[(size_t)(c0 + r + ty) * rows + r0 + tx] = f2bf(tile[tx][r + ty]);
}

// cache_v f32 [H][T][64] -> vt bf16 [H][64][T]
__global__ void vtrans_kernel(const float* __restrict__ vin,
                              unsigned short* __restrict__ vt) {
  __shared__ float tile[64][65];
  const int h = blockIdx.y;
  const int t0 = blockIdx.x * 64;
  const float* in = vin + (size_t)h * T_LEN * HDIM;
  unsigned short* out = vt + (size_t)h * HDIM * T_LEN;
  const int tx = threadIdx.x & 63, ty = threadIdx.x >> 6;
#pragma unroll
  for (int r = 0; r < 64; r += 4)
    tile[r + ty][tx] = in[(size_t)(t0 + r + ty) * HDIM + tx];
  __syncthreads();
#pragma unroll
  for (int r = 0; r < 64; r += 4)
    out[(size_t)(r + ty) * T_LEN + t0 + tx] = f2bf(tile[tx][r + ty]);
}

// ---------------------------------------------------------------- GEMM (B^T)
// MODE 0: c_attn epilogue (q*0.125*log2e->bf16, k->cache+bf16, v->cache).
// MODE 1: f32 out.
template <int MODE>
__global__ __launch_bounds__(256) void gemm_bt_kernel(
    const unsigned short* __restrict__ A, const unsigned short* __restrict__ Bt,
    const float* __restrict__ bias, int K,
    float* __restrict__ out_f32, unsigned short* __restrict__ qb,
    float* __restrict__ cache_k, float* __restrict__ cache_v,
    unsigned short* __restrict__ kb) {
  __shared__ alignas(16) unsigned short As[128 * 64];
  __shared__ alignas(16) unsigned short Bs[128 * 64];
  const int tid = threadIdx.x;
  const int lane = tid & 63;
  const int w = tid >> 6;
  const int wm = w >> 1, wn = w & 1;
  const int m0 = blockIdx.y * 128, n0 = blockIdx.x * 128;

  f32x4 acc[4][4];
#pragma unroll
  for (int i = 0; i < 4; ++i)
#pragma unroll
    for (int j = 0; j < 4; ++j) acc[i][j] = f32x4{0.f, 0.f, 0.f, 0.f};

  const int rbase = w * 8 + (lane >> 3);
  const int sbase = lane & 7;

  for (int k0 = 0; k0 < K; k0 += 64) {
#pragma unroll
    for (int q = 0; q < 4; ++q) {
      int row_l = q * 32 + rbase;
      int slot = sbase ^ (row_l & 7);
      const unsigned short* ga = A + (size_t)(m0 + row_l) * K + k0 + slot * 8;
      const unsigned short* gb = Bt + (size_t)(n0 + row_l) * K + k0 + slot * 8;
      unsigned int ldsOff = (unsigned int)(q * 4096 + w * 1024);
      GLOBAL_LOAD_LDS16(ga, (char*)As + ldsOff);
      GLOBAL_LOAD_LDS16(gb, (char*)Bs + ldsOff);
    }
    __syncthreads();
#pragma unroll
    for (int kk = 0; kk < 2; ++kk) {
      bf16x8 af[4], bfr[4];
#pragma unroll
      for (int mi = 0; mi < 4; ++mi) {
        int row = wm * 64 + mi * 16 + (lane & 15);
        int slot = (kk * 4 + (lane >> 4)) ^ (row & 7);
        af[mi] = *reinterpret_cast<const bf16x8*>((const char*)As + row * 128 + slot * 16);
      }
#pragma unroll
      for (int ni = 0; ni < 4; ++ni) {
        int row = wn * 64 + ni * 16 + (lane & 15);
        int slot = (kk * 4 + (lane >> 4)) ^ (row & 7);
        bfr[ni] = *reinterpret_cast<const bf16x8*>((const char*)Bs + row * 128 + slot * 16);
      }
#pragma unroll
      for (int mi = 0; mi < 4; ++mi)
#pragma unroll
        for (int ni = 0; ni < 4; ++ni)
          acc[mi][ni] = mfma_bf16(af[mi], bfr[ni], acc[mi][ni]);
    }
    __syncthreads();
  }

#pragma unroll
  for (int ni = 0; ni < 4; ++ni) {
    int n = n0 + wn * 64 + ni * 16 + (lane & 15);
    float bv = bias[n];
#pragma unroll
    for (int mi = 0; mi < 4; ++mi) {
#pragma unroll
      for (int r = 0; r < 4; ++r) {
        int m = m0 + wm * 64 + mi * 16 + (lane >> 4) * 4 + r;
        float val = acc[mi][ni][r] + bv;
        if (MODE == 0) {
          if (n < E_DIM) {
            // fold 1/sqrt(d) * log2(e) for exp2-softmax
            qb[(size_t)m * E_DIM + n] = f2bf(val * 0.18033688f);
          } else if (n < 2 * E_DIM) {
            int e = n - E_DIM;
            size_t idx = ((size_t)(e >> 6) * T_LEN + (PASTL + m)) * HDIM + (e & 63);
            cache_k[idx] = val;
            kb[idx] = f2bf(val);
          } else {
            int e = n - 2 * E_DIM;
            size_t idx = ((size_t)(e >> 6) * T_LEN + (PASTL + m)) * HDIM + (e & 63);
            cache_v[idx] = val;
          }
        } else {
          out_f32[(size_t)m * E_DIM + n] = val;
        }
      }
    }
  }
}

// ---------------------------------------------------------------- attention
// 4 waves (256 thr)/block, 32 q-rows/wave, KVBLK=64, 32x32x16 MFMA, swapped QK.
// P relayout fully in-register via v_permlane32_swap_b32 (no LDS, no selects).
// Softmax packs via v_cvt_pk_bf16_f32 (native). Mask code only in partial
// tiles (wave-uniform branch). Grid: 896 blocks, r9 chunks + XCD head-affinity.
__global__ __launch_bounds__(256, 4) void attn_kernel(
    const unsigned short* __restrict__ qb, const unsigned short* __restrict__ kb,
    const unsigned short* __restrict__ vt,
    unsigned short* __restrict__ o_part, float* __restrict__ l_part) {
  __shared__ alignas(16) unsigned short Ks[2][64 * 64];
  __shared__ alignas(16) unsigned short Vs[2][64 * 64];
  const int fid = blockIdx.x;  // 0..895
  const int h = (fid & 7) + ((fid >= 448) ? 8 : 0);
  const int g = (fid >> 3) - ((fid >= 448) ? 56 : 0);  // 0..55
  int x, c;
  if (g < 24) { x = g / 3; c = g - 3 * x; }
  else { int g2 = g - 24; x = 8 + (g2 >> 2); c = g2 & 3; }

  const int tid = threadIdx.x;
  const int w = tid >> 6;
  const int lane = tid & 63;
  const int l31 = lane & 31;
  const int hi = lane >> 5;
  const int hi4 = hi * 4;
  const int q0 = x * 128 + w * 32;

  // Q B-frags: lane (col=q=l31, hi) holds d = kk*16 + hi*8 + 0..7
  const unsigned short* qrow = qb + (size_t)(q0 + l31) * E_DIM + h * HDIM + hi * 8;
  bf16x8 qf[4];
#pragma unroll
  for (int kk = 0; kk < 4; ++kk)
    qf[kk] = *reinterpret_cast<const bf16x8*>(qrow + kk * 16);

  const unsigned short* kh = kb + (size_t)h * T_LEN * HDIM;
  const unsigned short* vh = vt + (size_t)h * HDIM * T_LEN;

  const int srow = tid >> 3;
  const int sseg = (tid & 7) ^ (srow & 7);
  const unsigned short* ksrc = kh + (size_t)srow * HDIM + sseg * 8;
  const unsigned short* vsrc = vh + (size_t)srow * T_LEN + sseg * 8;

  f32x16 o0, o1, zc;
#pragma unroll
  for (int i = 0; i < 16; ++i) { o0[i] = 0.f; o1[i] = 0.f; zc[i] = 0.f; }
  float lsum = 0.f;

  const int NTfull = 34 + 2 * x;
  const int tb = c * 16;
  const int te = (tb + 16 < NTfull) ? tb + 16 : NTfull;
  const int tbeg = tb * 64, tend = te * 64;
  const int qpp = q0 + l31 + PASTL;  // key > qpp => masked

  auto stage = [&](int b, int t0) {
    GLOBAL_LOAD_LDS16(ksrc + (size_t)t0 * HDIM, (char*)Ks[b] + tid * 16);
    GLOBAL_LOAD_LDS16(ksrc + (size_t)(t0 + 32) * HDIM, (char*)Ks[b] + 4096 + tid * 16);
    GLOBAL_LOAD_LDS16(vsrc + t0, (char*)Vs[b] + tid * 16);
    GLOBAL_LOAD_LDS16(vsrc + t0 + (size_t)32 * T_LEN, (char*)Vs[b] + 4096 + tid * 16);
  };

  stage(0, tbeg);
  int cur = 0;
  for (int t0 = tbeg; t0 < tend; t0 += 64) {
    asm volatile("s_waitcnt vmcnt(0)" ::: "memory");
    __syncthreads();
    if (t0 + 64 < tend) stage(cur ^ 1, t0 + 64);

    // ---- QK^T (swapped): A=K frags from LDS, B=Q regs; C starts at zc ----
    f32x16 s0, s1;
    __builtin_amdgcn_s_setprio(1);
    {
      int sl00 = (0 + hi) ^ (l31 & 7);
      bf16x8 kf0 = *reinterpret_cast<const bf16x8*>((const char*)Ks[cur] + l31 * 128 + sl00 * 16);
      bf16x8 kf1 = *reinterpret_cast<const bf16x8*>((const char*)Ks[cur] + (32 + l31) * 128 + sl00 * 16);
      s0 = mfma32(kf0, qf[0], zc);
      s1 = mfma32(kf1, qf[0], zc);
    }
#pragma unroll
    for (int kk = 1; kk < 4; ++kk) {
      int sl = (kk * 2 + hi) ^ (l31 & 7);
      bf16x8 kf0 = *reinterpret_cast<const bf16x8*>((const char*)Ks[cur] + l31 * 128 + sl * 16);
      bf16x8 kf1 = *reinterpret_cast<const bf16x8*>((const char*)Ks[cur] + (32 + l31) * 128 + sl * 16);
      s0 = mfma32(kf0, qf[kk], s0);
      s1 = mfma32(kf1, qf[kk], s1);
    }
    __builtin_amdgcn_s_setprio(0);

    // ---- V B-frags (independent of P; issue before softmax) ----
    bf16x8 vf0[4], vf1[4];
#pragma unroll
    for (int ks = 0; ks < 4; ++ks) {
      int sl = (ks * 2 + hi) ^ (l31 & 7);
      vf0[ks] = *reinterpret_cast<const bf16x8*>((const char*)Vs[cur] + l31 * 128 + sl * 16);
      vf1[ks] = *reinterpret_cast<const bf16x8*>((const char*)Vs[cur] + (32 + l31) * 128 + sl * 16);
    }

    // ---- softmax (no-max, exp2) + native packed cvt ----
    const bool partial = (t0 + 63 > q0 + PASTL);  // wave-uniform
    unsigned dw0[8], dw1[8];
    if (!partial) {
#pragma unroll
      for (int i = 0; i < 8; ++i) {
        int r0 = 2 * i;
        float p0 = __builtin_amdgcn_exp2f(s0[r0]);
        float p1 = __builtin_amdgcn_exp2f(s0[r0 + 1]);
        float p2 = __builtin_amdgcn_exp2f(s1[r0]);
        float p3 = __builtin_amdgcn_exp2f(s1[r0 + 1]);
        lsum += (p0 + p1) + (p2 + p3);
        dw0[i] = pkbf(p0, p1);
        dw1[i] = pkbf(p2, p3);
      }
    } else {
      const int thr = qpp - t0;
#pragma unroll
      for (int i = 0; i < 8; ++i) {
        int r0 = 2 * i;
        int ko = (r0 & 3) + 8 * (r0 >> 2) + hi4;
        float p0 = __builtin_amdgcn_exp2f(s0[r0]);
        float p1 = __builtin_amdgcn_exp2f(s0[r0 + 1]);
        float p2 = __builtin_amdgcn_exp2f(s1[r0]);
        float p3 = __builtin_amdgcn_exp2f(s1[r0 + 1]);
        if (ko > thr) p0 = 0.f;
        if (ko + 1 > thr) p1 = 0.f;
        if (ko + 32 > thr) p2 = 0.f;
        if (ko + 33 > thr) p3 = 0.f;
        lsum += (p0 + p1) + (p2 + p3);
        dw0[i] = pkbf(p0, p1);
        dw1[i] = pkbf(p2, p3);
      }
    }

    // ---- in-register P relayout: 8 permlane32_swap, both outputs used ----
    plswap(dw0[0], dw0[2]); plswap(dw0[1], dw0[3]);
    plswap(dw0[4], dw0[6]); plswap(dw0[5], dw0[7]);
    plswap(dw1[0], dw1[2]); plswap(dw1[1], dw1[3]);
    plswap(dw1[4], dw1[6]); plswap(dw1[5], dw1[7]);
    union U4 { unsigned u[4]; bf16x8 v; };
    U4 pu0, pu1, pu2, pu3;
    pu0.u[0] = dw0[0]; pu0.u[1] = dw0[1]; pu0.u[2] = dw0[2]; pu0.u[3] = dw0[3];
    pu1.u[0] = dw0[4]; pu1.u[1] = dw0[5]; pu1.u[2] = dw0[6]; pu1.u[3] = dw0[7];
    pu2.u[0] = dw1[0]; pu2.u[1] = dw1[1]; pu2.u[2] = dw1[2]; pu2.u[3] = dw1[3];
    pu3.u[0] = dw1[4]; pu3.u[1] = dw1[5]; pu3.u[2] = dw1[6]; pu3.u[3] = dw1[7];

    // ---- PV ----
    __builtin_amdgcn_s_setprio(1);
    o0 = mfma32(pu0.v, vf0[0], o0);
    o1 = mfma32(pu0.v, vf1[0], o1);
    o0 = mfma32(pu1.v, vf0[1], o0);
    o1 = mfma32(pu1.v, vf1[1], o1);
    o0 = mfma32(pu2.v, vf0[2], o0);
    o1 = mfma32(pu2.v, vf1[2], o1);
    o0 = mfma32(pu3.v, vf0[3], o0);
    o1 = mfma32(pu3.v, vf1[3], o1);
    __builtin_amdgcn_s_setprio(0);
    cur ^= 1;
  }

  lsum += __shfl_xor(lsum, 32);

  // partials: o_part[c][h][row][d] bf16, l_part[c][h][row] f32
  unsigned short* op = o_part + ((size_t)(c * NHEAD + h) * S_LEN) * HDIM;
  float* lp = l_part + (size_t)(c * NHEAD + h) * S_LEN;
  if (hi == 0) lp[q0 + l31] = lsum;
#pragma unroll
  for (int r = 0; r < 16; ++r) {
    int qr = (r & 3) + 8 * (r >> 2) + hi4;
    op[(size_t)(q0 + qr) * HDIM + l31] = f2bf(o0[r]);
    op[(size_t)(q0 + qr) * HDIM + 32 + l31] = f2bf(o1[r]);
  }
}

// Merge chunk partials (3 for rows<1024, 4 otherwise) and normalize -> ab bf16.
__global__ __launch_bounds__(256) void attn_merge_kernel(
    const unsigned short* __restrict__ o_part, const float* __restrict__ l_part,
    unsigned short* __restrict__ ab) {
  const int flat = blockIdx.x * 256 + threadIdx.x;
  const int d4 = flat & 15;
  const int row = (flat >> 4) & (S_LEN - 1);
  const int h = flat >> 15;
  const int nc = (row < 1024) ? 3 : 4;
  const size_t cstride_o = (size_t)NHEAD * S_LEN * HDIM;
  const size_t base_o = (((size_t)h * S_LEN) + row) * HDIM + d4 * 4;
  float acc[4] = {0.f, 0.f, 0.f, 0.f};
  float l = 0.f;
  for (int cc = 0; cc < nc; ++cc) {
    ushort4 u = *(const ushort4*)(o_part + cc * cstride_o + base_o);
    acc[0] += bf2f(u.x); acc[1] += bf2f(u.y);
    acc[2] += bf2f(u.z); acc[3] += bf2f(u.w);
    l += l_part[(size_t)cc * NHEAD * S_LEN + (size_t)h * S_LEN + row];
  }
  float inv = 1.f / l;
  ushort4 u;
  u.x = f2bf(acc[0] * inv);
  u.y = f2bf(acc[1] * inv);
  u.z = f2bf(acc[2] * inv);
  u.w = f2bf(acc[3] * inv);
  *(ushort4*)(ab + (size_t)row * E_DIM + h * HDIM + d4 * 4) = u;
}

// ---------------------------------------------------------------- launch

extern "C" void kernel_launch(void* const* d_in, const int* in_sizes, int n_in,
                              void* d_out, int out_size, void* d_ws, size_t ws_size,
                              hipStream_t stream) {
  (void)in_sizes; (void)n_in; (void)out_size; (void)ws_size;
  const float* x    = (const float*)d_in[0];
  const float* past = (const float*)d_in[1];
  const float* W1   = (const float*)d_in[2];
  const float* b1   = (const float*)d_in[3];
  const float* W2   = (const float*)d_in[4];
  const float* b2   = (const float*)d_in[5];

  float* out = (float*)d_out;
  float* cache_k = out + (size_t)S_LEN * E_DIM;
  float* cache_v = cache_k + (size_t)NHEAD * T_LEN * HDIM;

  // Workspace (~42.5 MB), lifetime-disjoint overlaps:
  //   [0,4)   xb -> ab ; [4,12) w1t -> vt ; [12,14) w2t
  //   [14,18) qb ; [18,26) kb ; [26,42) o_part bf16 [4][16][2048][64]
  //   [42,42.5) l_part f32 [4][16][2048]
  char* ws = (char*)d_ws;
  unsigned short* xb  = (unsigned short*)(ws);
  unsigned short* ab  = (unsigned short*)(ws);
  unsigned short* w1t = (unsigned short*)(ws + (size_t)(4u  << 20));
  unsigned short* vt  = (unsigned short*)(ws + (size_t)(4u  << 20));
  unsigned short* w2t = (unsigned short*)(ws + (size_t)(12u << 20));
  unsigned short* qb  = (unsigned short*)(ws + (size_t)(14u << 20));
  unsigned short* kb  = (unsigned short*)(ws + (size_t)(18u << 20));
  unsigned short* o_part = (unsigned short*)(ws + (size_t)(26u << 20));
  float* l_part = (float*)(ws + (size_t)(42u << 20));

  copy_past_kernel<<<2048, 256, 0, stream>>>(past, cache_k, kb);
  convert_kernel<<<1024, 256, 0, stream>>>(x, xb, (S_LEN * E_DIM) / 4);
  transpose_convert_kernel<<<dim3(3072 / 64, 1024 / 64), 256, 0, stream>>>(W1, w1t, 1024, 3072);
  transpose_convert_kernel<<<dim3(1024 / 64, 1024 / 64), 256, 0, stream>>>(W2, w2t, 1024, 1024);
  gemm_bt_kernel<0><<<dim3(3072 / 128, 2048 / 128), 256, 0, stream>>>(
      xb, w1t, b1, 1024, nullptr, qb, cache_k, cache_v, kb);
  vtrans_kernel<<<dim3(T_LEN / 64, NHEAD), 256, 0, stream>>>(cache_v, vt);
  attn_kernel<<<dim3(896), 256, 0, stream>>>(qb, kb, vt, o_part, l_part);
  attn_merge_kernel<<<(NHEAD * S_LEN * 16) / 256, 256, 0, stream>>>(o_part, l_part, ab);
  gemm_bt_kernel<1><<<dim3(1024 / 128, 2048 / 128), 256, 0, stream>>>(
      ab, w2t, b2, 1024, out, nullptr, nullptr, nullptr, nullptr);
}

// Round 12
// 136.225 us; speedup vs baseline: 1.2182x; 1.2182x over previous
//
#include <hip/hip_runtime.h>
#include <hip/hip_bf16.h>
#include <stdint.h>

// GPT2Attention: S=2048 E=1024 H=16 d=64 T=4096 past=2048, f32 in/out.
// Round 12: revert attn to r9 (best, 61us: 16x16 MFMA, sb-pair, LDS-P, chunked
// grid + XCD head-affinity) and apply 4-phase split-wait schedule (T3/T4):
// stageK/stageV separate; QK waits vmcnt(2) (V in flight), PV waits vmcnt(2)
// (next K in flight); raw s_barrier; no full drain in main loop.
// Also: copy_past+convert fused into one prep kernel (-1 launch).

#define S_LEN 2048
#define E_DIM 1024
#define NHEAD 16
#define HDIM  64
#define T_LEN 4096
#define PASTL 2048

typedef __bf16 bf16x8 __attribute__((ext_vector_type(8)));
typedef __bf16 bf16x4 __attribute__((ext_vector_type(4)));
typedef float  f32x4  __attribute__((ext_vector_type(4)));

static __device__ __forceinline__ f32x4 mfma_bf16(bf16x8 a, bf16x8 b, f32x4 c) {
  return __builtin_amdgcn_mfma_f32_16x16x32_bf16(a, b, c, 0, 0, 0);
}

// RNE float -> bf16 bits (values finite)
static __device__ __forceinline__ unsigned int f2bf(float f) {
  union { float f; unsigned int u; } v; v.f = f;
  unsigned int u = v.u;
  return (u + 0x7fffu + ((u >> 16) & 1u)) >> 16;
}

static __device__ __forceinline__ float bf2f(unsigned short u) {
  union { unsigned int u; float f; } v; v.u = (unsigned int)u << 16;
  return v.f;
}

#define GLOBAL_LOAD_LDS16(gptr, lptr)                                              \
  __builtin_amdgcn_global_load_lds(                                                \
      (const __attribute__((address_space(1))) unsigned int*)(gptr),               \
      (__attribute__((address_space(3))) unsigned int*)(lptr), 16, 0, 0)

// ---------------------------------------------------------------- aux kernels

// Fused: [0,n4p) copy past rows t<2048 -> cache (+bf16 K), [n4p,n4p+n4x) x->bf16.
__global__ void prep_kernel(const float* __restrict__ past,
                            const float* __restrict__ x,
                            float* __restrict__ cache,
                            unsigned short* __restrict__ kb,
                            unsigned short* __restrict__ xb) {
  const int n4p = (2 * NHEAD * PASTL * HDIM) / 4;
  const int n4x = (S_LEN * E_DIM) / 4;
  for (int i = blockIdx.x * blockDim.x + threadIdx.x; i < n4p + n4x;
       i += gridDim.x * blockDim.x) {
    if (i < n4p) {
      int e = i * 4;
      int d = e & 63;
      int t = (e >> 6) & (PASTL - 1);
      int hh = (e >> 17) & (NHEAD - 1);
      int kv = e >> 21;
      size_t full = (((size_t)kv * NHEAD + hh) * T_LEN + t) * HDIM + d;
      float4 v = *(const float4*)(past + full);
      *(float4*)(cache + full) = v;
      if (kv == 0) {
        ushort4 u;
        u.x = f2bf(v.x); u.y = f2bf(v.y); u.z = f2bf(v.z); u.w = f2bf(v.w);
        *(ushort4*)(kb + full) = u;
      }
    } else {
      int j = i - n4p;
      float4 v = ((const float4*)x)[j];
      ushort4 u;
      u.x = f2bf(v.x); u.y = f2bf(v.y); u.z = f2bf(v.z); u.w = f2bf(v.w);
      ((ushort4*)xb)[j] = u;
    }
  }
}

// in [rows][cols] f32 -> out [cols][rows] bf16
__global__ void transpose_convert_kernel(const float* __restrict__ in,
                                         unsigned short* __restrict__ out,
                                         int rows, int cols) {
  __shared__ float tile[64][65];
  const int c0 = blockIdx.x * 64, r0 = blockIdx.y * 64;
  const int tx = threadIdx.x & 63, ty = threadIdx.x >> 6;
#pragma unroll
  for (int r = 0; r < 64; r += 4)
    tile[r + ty][tx] = in[(size_t)(r0 + r + ty) * cols + c0 + tx];
  __syncthreads();
#pragma unroll
  for (int r = 0; r < 64; r += 4)
    out[(size_t)(c0 + r + ty) * rows + r0 + tx] = f2bf(tile[tx][r + ty]);
}

// cache_v f32 [H][T][64] -> vt bf16 [H][64][T]
__global__ void vtrans_kernel(const float* __restrict__ vin,
                              unsigned short* __restrict__ vt) {
  __shared__ float tile[64][65];
  const int h = blockIdx.y;
  const int t0 = blockIdx.x * 64;
  const float* in = vin + (size_t)h * T_LEN * HDIM;
  unsigned short* out = vt + (size_t)h * HDIM * T_LEN;
  const int tx = threadIdx.x & 63, ty = threadIdx.x >> 6;
#pragma unroll
  for (int r = 0; r < 64; r += 4)
    tile[r + ty][tx] = in[(size_t)(t0 + r + ty) * HDIM + tx];
  __syncthreads();
#pragma unroll
  for (int r = 0; r < 64; r += 4)
    out[(size_t)(r + ty) * T_LEN + t0 + tx] = f2bf(tile[tx][r + ty]);
}

// ---------------------------------------------------------------- GEMM (B^T)
// MODE 0: c_attn epilogue (q*0.125*log2e->bf16, k->cache+bf16, v->cache).
// MODE 1: f32 out.
template <int MODE>
__global__ __launch_bounds__(256) void gemm_bt_kernel(
    const unsigned short* __restrict__ A, const unsigned short* __restrict__ Bt,
    const float* __restrict__ bias, int K,
    float* __restrict__ out_f32, unsigned short* __restrict__ qb,
    float* __restrict__ cache_k, float* __restrict__ cache_v,
    unsigned short* __restrict__ kb) {
  __shared__ alignas(16) unsigned short As[128 * 64];
  __shared__ alignas(16) unsigned short Bs[128 * 64];
  const int tid = threadIdx.x;
  const int lane = tid & 63;
  const int w = tid >> 6;
  const int wm = w >> 1, wn = w & 1;
  const int m0 = blockIdx.y * 128, n0 = blockIdx.x * 128;

  f32x4 acc[4][4];
#pragma unroll
  for (int i = 0; i < 4; ++i)
#pragma unroll
    for (int j = 0; j < 4; ++j) acc[i][j] = f32x4{0.f, 0.f, 0.f, 0.f};

  const int rbase = w * 8 + (lane >> 3);
  const int sbase = lane & 7;

  for (int k0 = 0; k0 < K; k0 += 64) {
#pragma unroll
    for (int q = 0; q < 4; ++q) {
      int row_l = q * 32 + rbase;
      int slot = sbase ^ (row_l & 7);
      const unsigned short* ga = A + (size_t)(m0 + row_l) * K + k0 + slot * 8;
      const unsigned short* gb = Bt + (size_t)(n0 + row_l) * K + k0 + slot * 8;
      unsigned int ldsOff = (unsigned int)(q * 4096 + w * 1024);
      GLOBAL_LOAD_LDS16(ga, (char*)As + ldsOff);
      GLOBAL_LOAD_LDS16(gb, (char*)Bs + ldsOff);
    }
    __syncthreads();
#pragma unroll
    for (int kk = 0; kk < 2; ++kk) {
      bf16x8 af[4], bfr[4];
#pragma unroll
      for (int mi = 0; mi < 4; ++mi) {
        int row = wm * 64 + mi * 16 + (lane & 15);
        int slot = (kk * 4 + (lane >> 4)) ^ (row & 7);
        af[mi] = *reinterpret_cast<const bf16x8*>((const char*)As + row * 128 + slot * 16);
      }
#pragma unroll
      for (int ni = 0; ni < 4; ++ni) {
        int row = wn * 64 + ni * 16 + (lane & 15);
        int slot = (kk * 4 + (lane >> 4)) ^ (row & 7);
        bfr[ni] = *reinterpret_cast<const bf16x8*>((const char*)Bs + row * 128 + slot * 16);
      }
#pragma unroll
      for (int mi = 0; mi < 4; ++mi)
#pragma unroll
        for (int ni = 0; ni < 4; ++ni)
          acc[mi][ni] = mfma_bf16(af[mi], bfr[ni], acc[mi][ni]);
    }
    __syncthreads();
  }

#pragma unroll
  for (int ni = 0; ni < 4; ++ni) {
    int n = n0 + wn * 64 + ni * 16 + (lane & 15);
    float bv = bias[n];
#pragma unroll
    for (int mi = 0; mi < 4; ++mi) {
#pragma unroll
      for (int r = 0; r < 4; ++r) {
        int m = m0 + wm * 64 + mi * 16 + (lane >> 4) * 4 + r;
        float val = acc[mi][ni][r] + bv;
        if (MODE == 0) {
          if (n < E_DIM) {
            // fold 1/sqrt(d) * log2(e) for exp2-softmax
            qb[(size_t)m * E_DIM + n] = f2bf(val * 0.18033688f);
          } else if (n < 2 * E_DIM) {
            int e = n - E_DIM;
            size_t idx = ((size_t)(e >> 6) * T_LEN + (PASTL + m)) * HDIM + (e & 63);
            cache_k[idx] = val;
            kb[idx] = f2bf(val);
          } else {
            int e = n - 2 * E_DIM;
            size_t idx = ((size_t)(e >> 6) * T_LEN + (PASTL + m)) * HDIM + (e & 63);
            cache_v[idx] = val;
          }
        } else {
          out_f32[(size_t)m * E_DIM + n] = val;
        }
      }
    }
  }
}

// ---------------------------------------------------------------- attention
// r9 structure: 4 waves (256 thr)/block, 32 q-rows/wave (two 16-row sb),
// KVBLK=64, swapped QK^T (mfma(K,Q)), bf16x4 P writes to p_lds, pa reads.
// NEW: 4-phase split-wait schedule — stageK/stageV separate, counted vmcnt(2)
// before each compute phase (V resp. next-K stay in flight), raw s_barrier,
// vmcnt(0) only in the last iteration's PV wait.
// Grid: 896 blocks, 56 chunks/head (<=16 tiles), fid%8==head%8 XCD affinity.
__global__ __launch_bounds__(256) void attn_kernel(
    const unsigned short* __restrict__ qb, const unsigned short* __restrict__ kb,
    const unsigned short* __restrict__ vt,
    unsigned short* __restrict__ o_part, float* __restrict__ l_part) {
  __shared__ alignas(16) unsigned short Ks[2][64 * 64];
  __shared__ alignas(16) unsigned short Vs[2][64 * 64];
  __shared__ alignas(16) __bf16 p_lds[4][32][72];
  const int fid = blockIdx.x;  // 0..895
  const int h = (fid & 7) + ((fid >= 448) ? 8 : 0);
  const int g = (fid >> 3) - ((fid >= 448) ? 56 : 0);  // 0..55
  int x, c;
  if (g < 24) { x = g / 3; c = g - 3 * x; }
  else { int g2 = g - 24; x = 8 + (g2 >> 2); c = g2 & 3; }

  const int tid = threadIdx.x;
  const int w = tid >> 6;
  const int lane = tid & 63;
  const int lr = lane & 15;
  const int lg = lane >> 4;
  const int qb0 = x * 128;
  const int q0 = qb0 + w * 32;

  const unsigned short* qr0 = qb + (size_t)(q0 + lr) * E_DIM + h * HDIM + lg * 8;
  const unsigned short* qr1 = qb + (size_t)(q0 + 16 + lr) * E_DIM + h * HDIM + lg * 8;
  const bf16x8 qf00 = *reinterpret_cast<const bf16x8*>(qr0);
  const bf16x8 qf01 = *reinterpret_cast<const bf16x8*>(qr0 + 32);
  const bf16x8 qf10 = *reinterpret_cast<const bf16x8*>(qr1);
  const bf16x8 qf11 = *reinterpret_cast<const bf16x8*>(qr1 + 32);

  const unsigned short* kh = kb + (size_t)h * T_LEN * HDIM;
  const unsigned short* vh = vt + (size_t)h * HDIM * T_LEN;

  const int srow = tid >> 3;  // 0..31
  const int sseg = (tid & 7) ^ (srow & 7);
  const unsigned short* ksrc = kh + (size_t)srow * HDIM + sseg * 8;
  const unsigned short* vsrc = vh + (size_t)srow * T_LEN + sseg * 8;

  f32x4 o[2][4];
  float lsum[2][2];
#pragma unroll
  for (int sb = 0; sb < 2; ++sb) {
    lsum[sb][0] = lsum[sb][1] = 0.f;
#pragma unroll
    for (int jd = 0; jd < 4; ++jd) o[sb][jd] = f32x4{0.f, 0.f, 0.f, 0.f};
  }

  const int jmaxq = q0 + PASTL;
  const int NTfull = 34 + 2 * x;
  const int tb = c * 16;
  const int te = (tb + 16 < NTfull) ? tb + 16 : NTfull;
  const int NT = te - tb;   // >= 2
  const int tbeg = tb * 64;

  auto stageK = [&](int b, int t0) {
    GLOBAL_LOAD_LDS16(ksrc + (size_t)t0 * HDIM, (char*)Ks[b] + tid * 16);
    GLOBAL_LOAD_LDS16(ksrc + (size_t)(t0 + 32) * HDIM, (char*)Ks[b] + 4096 + tid * 16);
  };
  auto stageV = [&](int b, int t0) {
    GLOBAL_LOAD_LDS16(vsrc + t0, (char*)Vs[b] + tid * 16);
    GLOBAL_LOAD_LDS16(vsrc + t0 + (size_t)32 * T_LEN, (char*)Vs[b] + 4096 + tid * 16);
  };

  stageK(0, tbeg);
  stageV(0, tbeg);
  int cur = 0;
  int t0 = tbeg;
  for (int i = 0; i < NT; ++i, t0 += 64) {
    const bool more = (i + 1 < NT);
    // ---- phase 1: K ready (V of this tile still in flight) ----
    asm volatile("s_waitcnt vmcnt(2)" ::: "memory");
    __builtin_amdgcn_s_barrier();
    __builtin_amdgcn_sched_barrier(0);
    if (more) stageK(cur ^ 1, t0 + 64);

    bf16x8 kf[4][2];
#pragma unroll
    for (int j = 0; j < 4; ++j) {
      int row = j * 16 + lr;
      int s0 = lg ^ (row & 7), s1 = (4 + lg) ^ (row & 7);
      kf[j][0] = *reinterpret_cast<const bf16x8*>((const char*)Ks[cur] + row * 128 + s0 * 16);
      kf[j][1] = *reinterpret_cast<const bf16x8*>((const char*)Ks[cur] + row * 128 + s1 * 16);
    }

    f32x4 sc[2][4];
#pragma unroll
    for (int sb = 0; sb < 2; ++sb)
#pragma unroll
      for (int j = 0; j < 4; ++j) sc[sb][j] = f32x4{0.f, 0.f, 0.f, 0.f};
    __builtin_amdgcn_s_setprio(1);
#pragma unroll
    for (int j = 0; j < 4; ++j) {
      sc[0][j] = mfma_bf16(kf[j][0], qf00, sc[0][j]);
      sc[0][j] = mfma_bf16(kf[j][1], qf01, sc[0][j]);
      sc[1][j] = mfma_bf16(kf[j][0], qf10, sc[1][j]);
      sc[1][j] = mfma_bf16(kf[j][1], qf11, sc[1][j]);
    }
    __builtin_amdgcn_s_setprio(0);

    // ---- softmax -> p_lds (per-wave private; no barrier needed) ----
    const bool partial = (t0 + 63 > jmaxq);
    const int thr = q0 + PASTL - t0 + lr;
    const int lg4 = lg * 4;
#pragma unroll
    for (int sb = 0; sb < 2; ++sb) {
#pragma unroll
      for (int j = 0; j < 4; ++j) {
        bf16x4 pk;
#pragma unroll
        for (int r = 0; r < 4; ++r) {
          float p = __builtin_amdgcn_exp2f(sc[sb][j][r]);
          if (partial && (j * 16 + lg4 + r > thr + sb * 16)) p = 0.f;
          lsum[sb][r >> 1] += p;
          pk[r] = (__bf16)p;
        }
        *reinterpret_cast<bf16x4*>(&p_lds[w][sb * 16 + lr][j * 16 + lg4]) = pk;
      }
    }
    bf16x8 pa[2][2];
#pragma unroll
    for (int sb = 0; sb < 2; ++sb) {
      pa[sb][0] = *reinterpret_cast<const bf16x8*>(&p_lds[w][sb * 16 + lr][lg * 8]);
      pa[sb][1] = *reinterpret_cast<const bf16x8*>(&p_lds[w][sb * 16 + lr][32 + lg * 8]);
    }

    // ---- phase 2: V ready (next K in flight) ----
    if (more) {
      asm volatile("s_waitcnt vmcnt(2)" ::: "memory");
    } else {
      asm volatile("s_waitcnt vmcnt(0)" ::: "memory");
    }
    __builtin_amdgcn_s_barrier();
    __builtin_amdgcn_sched_barrier(0);
    if (more) stageV(cur ^ 1, t0 + 64);

    __builtin_amdgcn_s_setprio(1);
#pragma unroll
    for (int jd = 0; jd < 4; ++jd) {
      int row = jd * 16 + lr;
      int s0 = lg ^ (row & 7), s1 = (4 + lg) ^ (row & 7);
      bf16x8 vf0 = *reinterpret_cast<const bf16x8*>((const char*)Vs[cur] + row * 128 + s0 * 16);
      bf16x8 vf1 = *reinterpret_cast<const bf16x8*>((const char*)Vs[cur] + row * 128 + s1 * 16);
      o[0][jd] = mfma_bf16(pa[0][0], vf0, o[0][jd]);
      o[0][jd] = mfma_bf16(pa[0][1], vf1, o[0][jd]);
      o[1][jd] = mfma_bf16(pa[1][0], vf0, o[1][jd]);
      o[1][jd] = mfma_bf16(pa[1][1], vf1, o[1][jd]);
    }
    __builtin_amdgcn_s_setprio(0);
    cur ^= 1;
  }

  // partials: o_part[c][h][row][d] bf16, l_part[c][h][row] f32
  unsigned short* op = o_part + ((size_t)(c * NHEAD + h) * S_LEN) * HDIM;
  float* lp = l_part + (size_t)(c * NHEAD + h) * S_LEN;
#pragma unroll
  for (int sb = 0; sb < 2; ++sb) {
    float ls = lsum[sb][0] + lsum[sb][1];
    ls += __shfl_xor(ls, 16);
    ls += __shfl_xor(ls, 32);
    if (lg == 0) lp[q0 + sb * 16 + lr] = ls;
#pragma unroll
    for (int jd = 0; jd < 4; ++jd) {
#pragma unroll
      for (int r = 0; r < 4; ++r) {
        int row = q0 + sb * 16 + lg * 4 + r;
        op[(size_t)row * HDIM + jd * 16 + lr] = f2bf(o[sb][jd][r]);
      }
    }
  }
}

// Merge chunk partials (3 for rows<1024, 4 otherwise) and normalize -> ab bf16.
__global__ __launch_bounds__(256) void attn_merge_kernel(
    const unsigned short* __restrict__ o_part, const float* __restrict__ l_part,
    unsigned short* __restrict__ ab) {
  const int flat = blockIdx.x * 256 + threadIdx.x;
  const int d4 = flat & 15;
  const int row = (flat >> 4) & (S_LEN - 1);
  const int h = flat >> 15;
  const int nc = (row < 1024) ? 3 : 4;
  const size_t cstride_o = (size_t)NHEAD * S_LEN * HDIM;
  const size_t base_o = (((size_t)h * S_LEN) + row) * HDIM + d4 * 4;
  float acc[4] = {0.f, 0.f, 0.f, 0.f};
  float l = 0.f;
  for (int cc = 0; cc < nc; ++cc) {
    ushort4 u = *(const ushort4*)(o_part + cc * cstride_o + base_o);
    acc[0] += bf2f(u.x); acc[1] += bf2f(u.y);
    acc[2] += bf2f(u.z); acc[3] += bf2f(u.w);
    l += l_part[(size_t)cc * NHEAD * S_LEN + (size_t)h * S_LEN + row];
  }
  float inv = 1.f / l;
  ushort4 u;
  u.x = f2bf(acc[0] * inv);
  u.y = f2bf(acc[1] * inv);
  u.z = f2bf(acc[2] * inv);
  u.w = f2bf(acc[3] * inv);
  *(ushort4*)(ab + (size_t)row * E_DIM + h * HDIM + d4 * 4) = u;
}

// ---------------------------------------------------------------- launch

extern "C" void kernel_launch(void* const* d_in, const int* in_sizes, int n_in,
                              void* d_out, int out_size, void* d_ws, size_t ws_size,
                              hipStream_t stream) {
  (void)in_sizes; (void)n_in; (void)out_size; (void)ws_size;
  const float* x    = (const float*)d_in[0];
  const float* past = (const float*)d_in[1];
  const float* W1   = (const float*)d_in[2];
  const float* b1   = (const float*)d_in[3];
  const float* W2   = (const float*)d_in[4];
  const float* b2   = (const float*)d_in[5];

  float* out = (float*)d_out;
  float* cache_k = out + (size_t)S_LEN * E_DIM;
  float* cache_v = cache_k + (size_t)NHEAD * T_LEN * HDIM;

  // Workspace (~42.5 MB), lifetime-disjoint overlaps:
  //   [0,4)   xb -> ab ; [4,12) w1t -> vt ; [12,14) w2t
  //   [14,18) qb ; [18,26) kb ; [26,42) o_part bf16 [4][16][2048][64]
  //   [42,42.5) l_part f32 [4][16][2048]
  char* ws = (char*)d_ws;
  unsigned short* xb  = (unsigned short*)(ws);
  unsigned short* ab  = (unsigned short*)(ws);
  unsigned short* w1t = (unsigned short*)(ws + (size_t)(4u  << 20));
  unsigned short* vt  = (unsigned short*)(ws + (size_t)(4u  << 20));
  unsigned short* w2t = (unsigned short*)(ws + (size_t)(12u << 20));
  unsigned short* qb  = (unsigned short*)(ws + (size_t)(14u << 20));
  unsigned short* kb  = (unsigned short*)(ws + (size_t)(18u << 20));
  unsigned short* o_part = (unsigned short*)(ws + (size_t)(26u << 20));
  float* l_part = (float*)(ws + (size_t)(42u << 20));

  prep_kernel<<<2048, 256, 0, stream>>>(past, x, cache_k, kb, xb);
  transpose_convert_kernel<<<dim3(3072 / 64, 1024 / 64), 256, 0, stream>>>(W1, w1t, 1024, 3072);
  transpose_convert_kernel<<<dim3(1024 / 64, 1024 / 64), 256, 0, stream>>>(W2, w2t, 1024, 1024);
  gemm_bt_kernel<0><<<dim3(3072 / 128, 2048 / 128), 256, 0, stream>>>(
      xb, w1t, b1, 1024, nullptr, qb, cache_k, cache_v, kb);
  vtrans_kernel<<<dim3(T_LEN / 64, NHEAD), 256, 0, stream>>>(cache_v, vt);
  attn_kernel<<<dim3(896), 256, 0, stream>>>(qb, kb, vt, o_part, l_part);
  attn_merge_kernel<<<(NHEAD * S_LEN * 16) / 256, 256, 0, stream>>>(o_part, l_part, ab);
  gemm_bt_kernel<1><<<dim3(1024 / 128, 2048 / 128), 256, 0, stream>>>(
      ab, w2t, b2, 1024, out, nullptr, nullptr, nullptr, nullptr);
}